// Round 5
// baseline (6498.446 us; speedup 1.0000x reference)
//
#include <hip/hip_runtime.h>

// ---------------------------------------------------------------------------
// AttentionDecoder: 32-step GRU decoder with dual dot-product attention.
//   prologue: enc->bf16; kv GEMMs (global_load_lds, permuted [b][tt][512]);
//             Wf fold; ctx->h0; gi_x precompute
//   recurrence: ONE persistent kernel k_recur, 64 blocks (1 per batch row),
//               t-loop inside, all state (h, q, p, att, gi, gh) in LDS.
//               No launch gaps, no grid syncs (rows are independent).
//   epilogue: vocab GEMM -> d_out (f32)
// ---------------------------------------------------------------------------

typedef float    f32x4 __attribute__((ext_vector_type(4)));
typedef __bf16   bf16x8 __attribute__((ext_vector_type(8)));
typedef unsigned short u16x8 __attribute__((ext_vector_type(8)));

#define DEV __device__ __forceinline__

DEV unsigned short f2bf(float f) {
  unsigned u = __builtin_bit_cast(unsigned, f);
  u += 0x7fffu + ((u >> 16) & 1u);               // round-to-nearest-even
  return (unsigned short)(u >> 16);
}
DEV float bf2f(unsigned short h) {
  return __builtin_bit_cast(float, (unsigned)h << 16);
}
DEV bf16x8 as_bf(u16x8 v) { return __builtin_bit_cast(bf16x8, v); }
DEV u16x8 zero8() {
  u16x8 r = {0, 0, 0, 0, 0, 0, 0, 0};
  return r;
}
DEV u16x8 pack8(float4 a, float4 b) {
  u16x8 r;
  r[0]=f2bf(a.x); r[1]=f2bf(a.y); r[2]=f2bf(a.z); r[3]=f2bf(a.w);
  r[4]=f2bf(b.x); r[5]=f2bf(b.y); r[6]=f2bf(b.z); r[7]=f2bf(b.w);
  return r;
}
DEV void gload16(const void* g, void* l) {
  __builtin_amdgcn_global_load_lds(
      (const __attribute__((address_space(1))) void*)g,
      (__attribute__((address_space(3))) void*)l, 16, 0, 0);
}

// ------------------------------- converts ----------------------------------
__global__ __launch_bounds__(256) void k_cvt(const float* __restrict__ s,
                                             unsigned short* __restrict__ d, int n) {
  int i = (blockIdx.x * 256 + threadIdx.x) * 4;
  if (i + 4 <= n) {
    float4 v = *(const float4*)(s + i);
    d[i] = f2bf(v.x); d[i+1] = f2bf(v.y); d[i+2] = f2bf(v.z); d[i+3] = f2bf(v.w);
  } else {
    for (; i < n; i++) d[i] = f2bf(s[i]);
  }
}

// ctx_feat = [s1, s2, |s1-s2|, s1*s2]  -> bf16 [64, 16384]
__global__ __launch_bounds__(256) void k_build_ctx(const float* __restrict__ s1,
                                                   const float* __restrict__ s2,
                                                   unsigned short* __restrict__ ctx) {
  int j = blockIdx.x * 256 + threadIdx.x;     // < 64*16384
  int b = j >> 14, jj = j & 16383;
  int f = jj >> 12, k = jj & 4095;
  float a = s1[b * 4096 + k], c = s2[b * 4096 + k];
  float v = (f == 0) ? a : (f == 1) ? c : (f == 2) ? fabsf(a - c) : a * c;
  ctx[j] = f2bf(v);
}

// --------------- bf16 128x128 GEMM with global_load_lds staging -------------
// C[M,N] = A[M,K] * B[N,K]^T. grid (M/128, N/128).
// EPI 0: tanh(+bias), split at col 512, PERMUTED row store (tt*64+b -> b*128+tt)
// EPI 1: +bias -> f32 out, ld ofld
template<int EPI>
__global__ __launch_bounds__(256) void k_gemm_lds(
    const unsigned short* __restrict__ A, int lda,
    const unsigned short* __restrict__ B, int ldb, int K,
    unsigned short* __restrict__ obf0, unsigned short* __restrict__ obf1,
    float* __restrict__ of, int ofld,
    const float* __restrict__ bias0, const float* __restrict__ bias1)
{
  __shared__ __align__(16) unsigned short As[128 * 32];
  __shared__ __align__(16) unsigned short Bs[128 * 32];
  const int tid = threadIdx.x;
  const int r0 = blockIdx.x * 128, c0 = blockIdx.y * 128;
  const int lane = tid & 63, w = tid >> 6;
  const int wr = w >> 1, wc = w & 1;
  const int fr = lane & 15, fq = lane >> 4;
  f32x4 acc[4][4] = {};

  const int srow = tid >> 2, scol = (tid & 3) * 8;   // 64 rows x 4 chunks/row
  const unsigned short* gA0 = A + (size_t)(r0 + srow) * lda + scol;
  const unsigned short* gA1 = A + (size_t)(r0 + 64 + srow) * lda + scol;
  const unsigned short* gB0 = B + (size_t)(c0 + srow) * ldb + scol;
  const unsigned short* gB1 = B + (size_t)(c0 + 64 + srow) * ldb + scol;
  unsigned short* lA0 = As + tid * 8;
  unsigned short* lA1 = As + 2048 + tid * 8;
  unsigned short* lB0 = Bs + tid * 8;
  unsigned short* lB1 = Bs + 2048 + tid * 8;

  for (int k = 0; k < K; k += 32) {
    gload16(gA0 + k, lA0);
    gload16(gA1 + k, lA1);
    gload16(gB0 + k, lB0);
    gload16(gB1 + k, lB1);
    __syncthreads();

    u16x8 af[4], bfv[4];
    #pragma unroll
    for (int mi = 0; mi < 4; mi++)
      af[mi] = *(const u16x8*)&As[(wr * 64 + mi * 16 + fr) * 32 + fq * 8];
    #pragma unroll
    for (int nj = 0; nj < 4; nj++)
      bfv[nj] = *(const u16x8*)&Bs[(wc * 64 + nj * 16 + fr) * 32 + fq * 8];
    #pragma unroll
    for (int mi = 0; mi < 4; mi++)
      #pragma unroll
      for (int nj = 0; nj < 4; nj++)
        acc[mi][nj] = __builtin_amdgcn_mfma_f32_16x16x32_bf16(
            as_bf(af[mi]), as_bf(bfv[nj]), acc[mi][nj], 0, 0, 0);
    __syncthreads();
  }

  #pragma unroll
  for (int mi = 0; mi < 4; mi++)
  #pragma unroll
  for (int nj = 0; nj < 4; nj++) {
    f32x4 a = acc[mi][nj];
    #pragma unroll
    for (int j = 0; j < 4; j++) {
      int grow = r0 + wr * 64 + mi * 16 + fq * 4 + j;
      int gcol = c0 + wc * 64 + nj * 16 + fr;
      float v = a[j];
      if constexpr (EPI == 0) {
        float bias = gcol < 512 ? bias0[gcol] : bias1[gcol - 512];
        unsigned short r = f2bf(tanhf(v + bias));
        int prow = ((grow & 63) << 7) | (grow >> 6);     // tt*64+b -> b*128+tt
        (gcol < 512 ? obf0 : obf1)[(size_t)prow * 512 + (gcol & 511)] = r;
      } else {
        of[(size_t)grow * ofld + gcol] = v + bias0[gcol];
      }
    }
  }
}

// ------------------------- generic 128x128 MFMA GEMM ------------------------
// (h0 only: A bf16, B f32, raw f32 partials via z split-K)
template<int A_BF16, int B_BF16, int EPI>
__global__ __launch_bounds__(256) void k_gemm128(
    const void* __restrict__ Ap, int lda, const void* __restrict__ Bp, int ldb,
    int M, int N, int kper,
    unsigned short* __restrict__ obf0, unsigned short* __restrict__ obf1,
    float* __restrict__ of, const float* __restrict__ bias0,
    const float* __restrict__ bias1)
{
  __shared__ __align__(16) unsigned short As[128 * 32];
  __shared__ __align__(16) unsigned short Bs[128 * 32];
  const int tid = threadIdx.x;
  const int c0 = blockIdx.x * 128, r0 = blockIdx.y * 128;
  const int k0 = blockIdx.z * kper;
  if (EPI == 2) of += (size_t)blockIdx.z * M * N;

  const int lane = tid & 63, w = tid >> 6;
  const int wr = w >> 1, wc = w & 1;
  const int fr = lane & 15, fq = lane >> 4;

  f32x4 acc[4][4] = {};

  const int srow = tid >> 1, shalf = (tid & 1) * 16;

  for (int k = k0; k < k0 + kper; k += 32) {
    u16x8 a0, a1, b0, b1;
    {
      int gr = r0 + srow;
      if (gr < M) {
        if (A_BF16) {
          const unsigned short* a = (const unsigned short*)Ap + (size_t)gr * lda + k + shalf;
          a0 = *(const u16x8*)a; a1 = *(const u16x8*)(a + 8);
        } else {
          const float* a = (const float*)Ap + (size_t)gr * lda + k + shalf;
          float4 f0 = ((const float4*)a)[0], f1 = ((const float4*)a)[1];
          float4 f2 = ((const float4*)a)[2], f3 = ((const float4*)a)[3];
          a0 = pack8(f0, f1); a1 = pack8(f2, f3);
        }
      } else { a0 = zero8(); a1 = zero8(); }
    }
    {
      int gr = c0 + srow;
      if (B_BF16) {
        const unsigned short* p = (const unsigned short*)Bp + (size_t)gr * ldb + k + shalf;
        b0 = *(const u16x8*)p; b1 = *(const u16x8*)(p + 8);
      } else {
        const float* p = (const float*)Bp + (size_t)gr * ldb + k + shalf;
        float4 f0 = ((const float4*)p)[0], f1 = ((const float4*)p)[1];
        float4 f2 = ((const float4*)p)[2], f3 = ((const float4*)p)[3];
        b0 = pack8(f0, f1); b1 = pack8(f2, f3);
      }
    }
    *(u16x8*)&As[srow * 32 + shalf]     = a0;
    *(u16x8*)&As[srow * 32 + shalf + 8] = a1;
    *(u16x8*)&Bs[srow * 32 + shalf]     = b0;
    *(u16x8*)&Bs[srow * 32 + shalf + 8] = b1;
    __syncthreads();

    u16x8 af[4], bfv[4];
    #pragma unroll
    for (int mi = 0; mi < 4; mi++)
      af[mi] = *(const u16x8*)&As[(wr * 64 + mi * 16 + fr) * 32 + fq * 8];
    #pragma unroll
    for (int nj = 0; nj < 4; nj++)
      bfv[nj] = *(const u16x8*)&Bs[(wc * 64 + nj * 16 + fr) * 32 + fq * 8];
    #pragma unroll
    for (int mi = 0; mi < 4; mi++)
      #pragma unroll
      for (int nj = 0; nj < 4; nj++)
        acc[mi][nj] = __builtin_amdgcn_mfma_f32_16x16x32_bf16(
            as_bf(af[mi]), as_bf(bfv[nj]), acc[mi][nj], 0, 0, 0);
    __syncthreads();
  }

  #pragma unroll
  for (int mi = 0; mi < 4; mi++)
  #pragma unroll
  for (int nj = 0; nj < 4; nj++) {
    f32x4 a = acc[mi][nj];
    #pragma unroll
    for (int j = 0; j < 4; j++) {
      int grow = r0 + wr * 64 + mi * 16 + fq * 4 + j;
      int gcol = c0 + wc * 64 + nj * 16 + fr;
      if (grow < M) {
        float v = a[j];
        if constexpr (EPI == 1) {
          of[(size_t)grow * N + gcol] = v + bias0[gcol];
        } else if constexpr (EPI == 2) {
          of[(size_t)grow * N + gcol] = v;
        }
      }
    }
  }
}

__global__ __launch_bounds__(256) void k_reduce_h0(const float* __restrict__ part,
                                                   const float* __restrict__ b_ctx,
                                                   float* __restrict__ h) {
  int j = blockIdx.x * 256 + threadIdx.x;   // < 64*512
  float s = b_ctx[j & 511];
  for (int z = 0; z < 8; z++) s += part[z * 32768 + j];
  h[j] = s;
}

// ------------------- W_f = W_ih @ W_in  fold (one-time) ---------------------
__global__ __launch_bounds__(256) void k_wf(const float* __restrict__ W_ih,
                                            const float* __restrict__ W_in,
                                            unsigned short* __restrict__ wf_att,
                                            float* __restrict__ wfx) {
  __shared__ float wl[8][512];
  int ic = blockIdx.x, jc = blockIdx.y, tid = threadIdx.x;
  for (int x = tid; x < 8 * 512; x += 256)
    wl[x >> 9][x & 511] = W_ih[(ic * 8 + (x >> 9)) * 512 + (x & 511)];
  __syncthreads();
  int j = jc * 256 + tid;
  if (j >= 1324) return;
  float acc[8] = {};
  for (int d = 0; d < 512; d++) {
    float win = W_in[d * 1324 + j];
    #pragma unroll
    for (int r = 0; r < 8; r++) acc[r] += wl[r][d] * win;
  }
  for (int r = 0; r < 8; r++) {
    int i = ic * 8 + r;
    if (j < 300) wfx[i * 300 + j] = acc[r];
    else         wf_att[i * 1024 + (j - 300)] = f2bf(acc[r]);
  }
}

__global__ __launch_bounds__(256) void k_bfull(const float* __restrict__ W_ih,
                                               const float* __restrict__ b_in,
                                               const float* __restrict__ b_ih,
                                               float* __restrict__ bfull) {
  int i = blockIdx.x * 256 + threadIdx.x;   // < 1536
  if (i >= 1536) return;
  float acc = b_ih[i];
  for (int d = 0; d < 512; d++) acc += W_ih[i * 512 + d] * b_in[d];
  bfull[i] = acc;
}

// gi_x[t*64+b, :] = expl[t,b,:300] @ Wfx^T   (all steps precomputed)
__global__ __launch_bounds__(256) void k_gix(const float* __restrict__ expl,
                                             const float* __restrict__ wfx,
                                             float* __restrict__ gi_x) {
  __shared__ float el[16][300];
  int rc = blockIdx.x, ic = blockIdx.y, tid = threadIdx.x;
  for (int x = tid; x < 16 * 300; x += 256)
    el[x / 300][x % 300] = expl[(size_t)(rc * 16 + x / 300) * 300 + (x % 300)];
  __syncthreads();
  int c = ic * 256 + tid;    // < 1536 exactly
  float acc[16] = {};
  for (int k = 0; k < 300; k++) {
    float wv = wfx[c * 300 + k];
    #pragma unroll
    for (int r = 0; r < 16; r++) acc[r] += el[r][k] * wv;
  }
  for (int r = 0; r < 16; r++) gi_x[(size_t)(rc * 16 + r) * 1536 + c] = acc[r];
}

// ---------------------- persistent recurrence kernel ------------------------
// 64 blocks (one per batch row) x 1024 threads; t-loop internal. All state in
// LDS. Per step: q -> scores -> softmax -> att -> gi/gh (balanced col+K split)
// -> GRU -> hs, outs[t].
__global__ __launch_bounds__(1024) void k_recur(
    const float* __restrict__ h0,
    const unsigned short* __restrict__ wq,
    const float* __restrict__ bq1, const float* __restrict__ bq2,
    const unsigned short* __restrict__ keys1, const unsigned short* __restrict__ keys2,
    const unsigned short* __restrict__ vals1, const unsigned short* __restrict__ vals2,
    const unsigned short* __restrict__ wf_att, const unsigned short* __restrict__ whh,
    const float* __restrict__ b_hh, const float* __restrict__ gi_x,
    const float* __restrict__ bfull, unsigned short* __restrict__ outs_bf)
{
  const int b = blockIdx.x, tid = threadIdx.x;
  __shared__ float hs[512];
  __shared__ float qs[1024];
  __shared__ float pr[256];
  __shared__ __align__(16) unsigned short att_s[1024];
  __shared__ float gis[1536];
  __shared__ float ghs[1536];
  __shared__ float partG[1024];
  __shared__ float partH[1024];

  if (tid < 512) hs[tid] = h0[b * 512 + tid];
  __syncthreads();

  const unsigned short* k1b = keys1 + (size_t)b * 128 * 512;
  const unsigned short* k2b = keys2 + (size_t)b * 128 * 512;
  const unsigned short* v1b = vals1 + (size_t)b * 128 * 512;
  const unsigned short* v2b = vals2 + (size_t)b * 128 * 512;
  const int u = tid & 511, kh = tid >> 9;    // K-split id for odd 512 cols

  for (int t = 0; t < 32; t++) {
    // ---- q: 1 output per thread (tid = side*512 + a) ----
    {
      const u16x8* wrow = (const u16x8*)(wq + ((size_t)tid << 9));
      float acc0 = 0.f, acc1 = 0.f;
      #pragma unroll 4
      for (int k8 = 0; k8 < 64; k8 += 2) {
        u16x8 w0 = wrow[k8], w1 = wrow[k8 + 1];
        #pragma unroll
        for (int j = 0; j < 8; j++) {
          acc0 += hs[k8 * 8 + j]     * bf2f(w0[j]);
          acc1 += hs[k8 * 8 + 8 + j] * bf2f(w1[j]);
        }
      }
      qs[tid] = tanhf(acc0 + acc1 + (tid < 512 ? bq1[u] : bq2[u]));
    }
    __syncthreads();

    // ---- scores: 256 outputs ----
    if (tid < 256) {
      int side = tid >> 7, tt = tid & 127;
      const u16x8* krow = (const u16x8*)((side ? k2b : k1b) + (size_t)tt * 512);
      const float* q = qs + (side << 9);
      float acc0 = 0.f, acc1 = 0.f;
      #pragma unroll 4
      for (int k8 = 0; k8 < 64; k8 += 2) {
        u16x8 w0 = krow[k8], w1 = krow[k8 + 1];
        #pragma unroll
        for (int j = 0; j < 8; j++) {
          acc0 += q[k8 * 8 + j]     * bf2f(w0[j]);
          acc1 += q[k8 * 8 + 8 + j] * bf2f(w1[j]);
        }
      }
      pr[tid] = acc0 + acc1;
    }
    __syncthreads();

    // ---- softmax per side (wave 0 side 0, wave 1 side 1) ----
    if (tid < 128) {
      int side = tid >> 6, l = tid & 63;
      float s0 = pr[side * 128 + l], s1 = pr[side * 128 + 64 + l];
      float m = fmaxf(s0, s1);
      #pragma unroll
      for (int off = 32; off; off >>= 1) m = fmaxf(m, __shfl_xor(m, off));
      float e0 = __expf(s0 - m), e1 = __expf(s1 - m);
      float ss = e0 + e1;
      #pragma unroll
      for (int off = 32; off; off >>= 1) ss += __shfl_xor(ss, off);
      float inv = 1.f / ss;
      pr[side * 128 + l] = e0 * inv;
      pr[side * 128 + 64 + l] = e1 * inv;
    }
    __syncthreads();

    // ---- att: 1 output per thread -> att_s[side*512+a] (bf16) ----
    {
      const unsigned short* vcol = (tid < 512 ? v1b : v2b) + u;
      const float* p = pr + ((tid >> 9) << 7);
      float acc0 = 0.f, acc1 = 0.f;
      #pragma unroll 4
      for (int tt = 0; tt < 128; tt += 2) {
        acc0 += p[tt]     * bf2f(vcol[(size_t)tt * 512]);
        acc1 += p[tt + 1] * bf2f(vcol[(size_t)(tt + 1) * 512]);
      }
      att_s[tid] = f2bf(acc0 + acc1);
    }
    __syncthreads();

    // ---- gi cols 0..1023 (full K=1024) ----
    {
      const u16x8* wrow = (const u16x8*)(wf_att + ((size_t)tid << 10));
      const u16x8* arow = (const u16x8*)att_s;
      float acc0 = 0.f, acc1 = 0.f;
      #pragma unroll 4
      for (int k8 = 0; k8 < 128; k8 += 2) {
        u16x8 w0 = wrow[k8], w1 = wrow[k8 + 1];
        u16x8 a0 = arow[k8], a1 = arow[k8 + 1];
        #pragma unroll
        for (int j = 0; j < 8; j++) {
          acc0 += bf2f(a0[j]) * bf2f(w0[j]);
          acc1 += bf2f(a1[j]) * bf2f(w1[j]);
        }
      }
      size_t gb = (size_t)(t * 64 + b) * 1536;
      gis[tid] = acc0 + acc1 + gi_x[gb + tid] + bfull[tid];
    }
    // ---- gi cols 1024..1535: K-split halves ----
    {
      const u16x8* wrow = (const u16x8*)(wf_att + (size_t)(1024 + u) * 1024 + (kh << 9));
      const u16x8* arow = (const u16x8*)(att_s + (kh << 9));
      float acc0 = 0.f, acc1 = 0.f;
      #pragma unroll 4
      for (int k8 = 0; k8 < 64; k8 += 2) {
        u16x8 w0 = wrow[k8], w1 = wrow[k8 + 1];
        u16x8 a0 = arow[k8], a1 = arow[k8 + 1];
        #pragma unroll
        for (int j = 0; j < 8; j++) {
          acc0 += bf2f(a0[j]) * bf2f(w0[j]);
          acc1 += bf2f(a1[j]) * bf2f(w1[j]);
        }
      }
      partG[tid] = acc0 + acc1;
    }
    // ---- gh cols 0..1023 (full K=512) ----
    {
      const u16x8* wrow = (const u16x8*)(whh + ((size_t)tid << 9));
      float acc0 = 0.f, acc1 = 0.f;
      #pragma unroll 4
      for (int k8 = 0; k8 < 64; k8 += 2) {
        u16x8 w0 = wrow[k8], w1 = wrow[k8 + 1];
        #pragma unroll
        for (int j = 0; j < 8; j++) {
          acc0 += hs[k8 * 8 + j]     * bf2f(w0[j]);
          acc1 += hs[k8 * 8 + 8 + j] * bf2f(w1[j]);
        }
      }
      ghs[tid] = acc0 + acc1 + b_hh[tid];
    }
    // ---- gh cols 1024..1535: K-split halves ----
    {
      const u16x8* wrow = (const u16x8*)(whh + (size_t)(1024 + u) * 512 + (kh << 8));
      const float* hh = hs + (kh << 8);
      float acc0 = 0.f, acc1 = 0.f;
      #pragma unroll 4
      for (int k8 = 0; k8 < 32; k8 += 2) {
        u16x8 w0 = wrow[k8], w1 = wrow[k8 + 1];
        #pragma unroll
        for (int j = 0; j < 8; j++) {
          acc0 += hh[k8 * 8 + j]     * bf2f(w0[j]);
          acc1 += hh[k8 * 8 + 8 + j] * bf2f(w1[j]);
        }
      }
      partH[tid] = acc0 + acc1;
    }
    __syncthreads();

    // ---- combine K-split partials ----
    if (tid < 512) {
      size_t gb = (size_t)(t * 64 + b) * 1536;
      gis[1024 + tid] = partG[tid] + partG[512 + tid] + gi_x[gb + 1024 + tid] + bfull[1024 + tid];
      ghs[1024 + tid] = partH[tid] + partH[512 + tid] + b_hh[1024 + tid];
    }
    __syncthreads();

    // ---- GRU -> h(t), outs[t] ----
    if (tid < 512) {
      int d = tid;
      float ir = gis[d], iz = gis[512 + d], inn = gis[1024 + d];
      float hr = ghs[d], hz = ghs[512 + d], hn = ghs[1024 + d];
      float ho = hs[d];
      float r = 1.f / (1.f + expf(-(ir + hr)));
      float z = 1.f / (1.f + expf(-(iz + hz)));
      float n = tanhf(inn + r * hn);
      float hv = (1.f - z) * n + z * ho;
      hs[d] = hv;
      outs_bf[(size_t)(t * 64 + b) * 512 + d] = f2bf(hv);
    }
    __syncthreads();
  }
}

// ---------------------------------------------------------------------------
extern "C" void kernel_launch(void* const* d_in, const int* in_sizes, int n_in,
                              void* d_out, int out_size, void* d_ws, size_t ws_size,
                              hipStream_t stream) {
  const float* expl  = (const float*)d_in[0];
  const float* enc1  = (const float*)d_in[1];
  const float* enc2  = (const float*)d_in[2];
  const float* s1e   = (const float*)d_in[3];
  const float* s2e   = (const float*)d_in[4];
  const float* W_ctx = (const float*)d_in[5];
  const float* b_ctx = (const float*)d_in[6];
  const float* Wq1   = (const float*)d_in[7];
  const float* bq1   = (const float*)d_in[8];
  const float* Wk1   = (const float*)d_in[9];
  const float* bk1   = (const float*)d_in[10];
  const float* Wv1   = (const float*)d_in[11];
  const float* bv1   = (const float*)d_in[12];
  const float* Wq2   = (const float*)d_in[13];
  const float* bq2   = (const float*)d_in[14];
  const float* Wk2   = (const float*)d_in[15];
  const float* bk2   = (const float*)d_in[16];
  const float* Wv2   = (const float*)d_in[17];
  const float* bv2   = (const float*)d_in[18];
  const float* W_in  = (const float*)d_in[19];
  const float* b_in  = (const float*)d_in[20];
  const float* W_ih  = (const float*)d_in[21];
  const float* b_ih  = (const float*)d_in[22];
  const float* W_hh  = (const float*)d_in[23];
  const float* b_hh  = (const float*)d_in[24];
  const float* W_voc = (const float*)d_in[25];
  const float* b_voc = (const float*)d_in[26];
  float* out = (float*)d_out;

  char* ws = (char*)d_ws;
  unsigned short* keys1  = (unsigned short*)(ws + 0);          // [b][tt][512]
  unsigned short* vals1  = (unsigned short*)(ws + 8388608);
  unsigned short* keys2  = (unsigned short*)(ws + 16777216);
  unsigned short* vals2  = (unsigned short*)(ws + 25165824);
  unsigned short* encbf  = (unsigned short*)(ws + 33554432);   // 67.1 MB
  unsigned short* wkv    = (unsigned short*)(ws + 100663296);  // 8.4 MB
  unsigned short* wvoc   = (unsigned short*)(ws + 109051904);  // 32.8 MB
  unsigned short* whh    = (unsigned short*)(ws + 141819904);
  unsigned short* wq     = (unsigned short*)(ws + 143392768);
  unsigned short* wf_att = (unsigned short*)(ws + 144441344);  // [1536][1024]
  float*          wfx    = (float*)(ws + 147587072);
  float*          bfull  = (float*)(ws + 149430272);
  float*          gi_x   = (float*)(ws + 149436416);           // 12.6 MB
  unsigned short* ctx_bf = (unsigned short*)(ws + 162019328);
  float*          part   = (float*)(ws + 164116480);
  float*          hA     = (float*)(ws + 165165056);
  unsigned short* outs_bf= (unsigned short*)(ws + 166213632);  // 2 MB
  // total ws use ~168.3 MB

  auto cvt = [&](const float* s, unsigned short* d, int n) {
    k_cvt<<<(n + 1023) / 1024, 256, 0, stream>>>(s, d, n);
  };

  // ---- keys/vals side 1 ----
  cvt(enc1, encbf, 8192 * 4096);
  cvt(Wk1, wkv, 512 * 4096);
  cvt(Wv1, wkv + 512 * 4096, 512 * 4096);
  k_gemm_lds<0><<<dim3(64, 8), 256, 0, stream>>>(
      encbf, 4096, wkv, 4096, 4096, keys1, vals1, nullptr, 0, bk1, bv1);
  // ---- keys/vals side 2 ----
  cvt(enc2, encbf, 8192 * 4096);
  cvt(Wk2, wkv, 512 * 4096);
  cvt(Wv2, wkv + 512 * 4096, 512 * 4096);
  k_gemm_lds<0><<<dim3(64, 8), 256, 0, stream>>>(
      encbf, 4096, wkv, 4096, 4096, keys2, vals2, nullptr, 0, bk2, bv2);

  // ---- other weight converts ----
  cvt(W_voc, wvoc, 32000 * 512);
  cvt(W_hh, whh, 1536 * 512);
  cvt(Wq1, wq, 512 * 512);
  cvt(Wq2, wq + 512 * 512, 512 * 512);

  // ---- Wf fold + gi_x ----
  k_wf<<<dim3(192, 6), 256, 0, stream>>>(W_ih, W_in, wf_att, wfx);
  k_bfull<<<6, 256, 0, stream>>>(W_ih, b_in, b_ih, bfull);
  k_gix<<<dim3(128, 6), 256, 0, stream>>>(expl, wfx, gi_x);

  // ---- h0 ----
  k_build_ctx<<<4096, 256, 0, stream>>>(s1e, s2e, ctx_bf);
  k_gemm128<1, 0, 2><<<dim3(4, 1, 8), 256, 0, stream>>>(
      ctx_bf, 16384, W_ctx, 16384, 64, 512, 2048,
      nullptr, nullptr, part, nullptr, nullptr);
  k_reduce_h0<<<128, 256, 0, stream>>>(part, b_ctx, hA);

  // ---- recurrence: ONE persistent kernel ----
  k_recur<<<64, 1024, 0, stream>>>(hA, wq, bq1, bq2, keys1, keys2, vals1, vals2,
                                   wf_att, whh, b_hh, gi_x, bfull, outs_bf);

  // ---- logits = outs @ W_voc^T + b_voc ----
  k_gemm_lds<1><<<dim3(16, 250), 256, 0, stream>>>(
      outs_bf, 512, wvoc, 512, 512, nullptr, nullptr, out, 32000, b_voc, nullptr);
}

// Round 6
// 2080.710 us; speedup vs baseline: 3.1232x; 3.1232x over previous
//
#include <hip/hip_runtime.h>

// ---------------------------------------------------------------------------
// AttentionDecoder. Key law (R5 post-mortem): recurrence weights must be read
// ONCE per step -> column-sliced kernels over all 64 batch rows.
//   per step: K1 k_mv64<0> (40 blk): [q|gh] = h @ [Wq1;Wq2;Whh]^T (MFMA M=64)
//             K2 k_att    (128 blk): scores/softmax/att per (b,side)
//             K3 k_mv64<1> (24 blk): gi = att @ Wf^T + gi_x + bfull
//             K0 k_gru    (64 blk):  GRU elementwise, h f32 + h_bf
// ---------------------------------------------------------------------------

typedef float    f32x4 __attribute__((ext_vector_type(4)));
typedef __bf16   bf16x8 __attribute__((ext_vector_type(8)));
typedef unsigned short u16x8 __attribute__((ext_vector_type(8)));

#define DEV __device__ __forceinline__

DEV unsigned short f2bf(float f) {
  unsigned u = __builtin_bit_cast(unsigned, f);
  u += 0x7fffu + ((u >> 16) & 1u);
  return (unsigned short)(u >> 16);
}
DEV float bf2f(unsigned short h) {
  return __builtin_bit_cast(float, (unsigned)h << 16);
}
DEV bf16x8 as_bf(u16x8 v) { return __builtin_bit_cast(bf16x8, v); }
DEV u16x8 zero8() {
  u16x8 r = {0, 0, 0, 0, 0, 0, 0, 0};
  return r;
}
DEV u16x8 pack8(float4 a, float4 b) {
  u16x8 r;
  r[0]=f2bf(a.x); r[1]=f2bf(a.y); r[2]=f2bf(a.z); r[3]=f2bf(a.w);
  r[4]=f2bf(b.x); r[5]=f2bf(b.y); r[6]=f2bf(b.z); r[7]=f2bf(b.w);
  return r;
}
DEV void gload16(const void* g, void* l) {
  __builtin_amdgcn_global_load_lds(
      (const __attribute__((address_space(1))) void*)g,
      (__attribute__((address_space(3))) void*)l, 16, 0, 0);
}

// ------------------------------- converts ----------------------------------
__global__ __launch_bounds__(256) void k_cvt(const float* __restrict__ s,
                                             unsigned short* __restrict__ d, int n) {
  int i = (blockIdx.x * 256 + threadIdx.x) * 4;
  if (i + 4 <= n) {
    float4 v = *(const float4*)(s + i);
    d[i] = f2bf(v.x); d[i+1] = f2bf(v.y); d[i+2] = f2bf(v.z); d[i+3] = f2bf(v.w);
  } else {
    for (; i < n; i++) d[i] = f2bf(s[i]);
  }
}

// ctx_feat = [s1, s2, |s1-s2|, s1*s2]  -> bf16 [64, 16384]
__global__ __launch_bounds__(256) void k_build_ctx(const float* __restrict__ s1,
                                                   const float* __restrict__ s2,
                                                   unsigned short* __restrict__ ctx) {
  int j = blockIdx.x * 256 + threadIdx.x;
  int b = j >> 14, jj = j & 16383;
  int f = jj >> 12, k = jj & 4095;
  float a = s1[b * 4096 + k], c = s2[b * 4096 + k];
  float v = (f == 0) ? a : (f == 1) ? c : (f == 2) ? fabsf(a - c) : a * c;
  ctx[j] = f2bf(v);
}

// --------------- bf16 128x128 GEMM with global_load_lds staging -------------
// EPI 0: tanh(+bias), split col 512, PERMUTED rows (tt*64+b -> b*128+tt)
// EPI 1: +bias -> f32, ld ofld
template<int EPI>
__global__ __launch_bounds__(256) void k_gemm_lds(
    const unsigned short* __restrict__ A, int lda,
    const unsigned short* __restrict__ B, int ldb, int K,
    unsigned short* __restrict__ obf0, unsigned short* __restrict__ obf1,
    float* __restrict__ of, int ofld,
    const float* __restrict__ bias0, const float* __restrict__ bias1)
{
  __shared__ __align__(16) unsigned short As[128 * 32];
  __shared__ __align__(16) unsigned short Bs[128 * 32];
  const int tid = threadIdx.x;
  const int r0 = blockIdx.x * 128, c0 = blockIdx.y * 128;
  const int lane = tid & 63, w = tid >> 6;
  const int wr = w >> 1, wc = w & 1;
  const int fr = lane & 15, fq = lane >> 4;
  f32x4 acc[4][4] = {};

  const int srow = tid >> 2, scol = (tid & 3) * 8;
  const unsigned short* gA0 = A + (size_t)(r0 + srow) * lda + scol;
  const unsigned short* gA1 = A + (size_t)(r0 + 64 + srow) * lda + scol;
  const unsigned short* gB0 = B + (size_t)(c0 + srow) * ldb + scol;
  const unsigned short* gB1 = B + (size_t)(c0 + 64 + srow) * ldb + scol;
  unsigned short* lA0 = As + tid * 8;
  unsigned short* lA1 = As + 2048 + tid * 8;
  unsigned short* lB0 = Bs + tid * 8;
  unsigned short* lB1 = Bs + 2048 + tid * 8;

  for (int k = 0; k < K; k += 32) {
    gload16(gA0 + k, lA0);
    gload16(gA1 + k, lA1);
    gload16(gB0 + k, lB0);
    gload16(gB1 + k, lB1);
    __syncthreads();

    u16x8 af[4], bfv[4];
    #pragma unroll
    for (int mi = 0; mi < 4; mi++)
      af[mi] = *(const u16x8*)&As[(wr * 64 + mi * 16 + fr) * 32 + fq * 8];
    #pragma unroll
    for (int nj = 0; nj < 4; nj++)
      bfv[nj] = *(const u16x8*)&Bs[(wc * 64 + nj * 16 + fr) * 32 + fq * 8];
    #pragma unroll
    for (int mi = 0; mi < 4; mi++)
      #pragma unroll
      for (int nj = 0; nj < 4; nj++)
        acc[mi][nj] = __builtin_amdgcn_mfma_f32_16x16x32_bf16(
            as_bf(af[mi]), as_bf(bfv[nj]), acc[mi][nj], 0, 0, 0);
    __syncthreads();
  }

  #pragma unroll
  for (int mi = 0; mi < 4; mi++)
  #pragma unroll
  for (int nj = 0; nj < 4; nj++) {
    f32x4 a = acc[mi][nj];
    #pragma unroll
    for (int j = 0; j < 4; j++) {
      int grow = r0 + wr * 64 + mi * 16 + fq * 4 + j;
      int gcol = c0 + wc * 64 + nj * 16 + fr;
      float v = a[j];
      if constexpr (EPI == 0) {
        float bias = gcol < 512 ? bias0[gcol] : bias1[gcol - 512];
        unsigned short r = f2bf(tanhf(v + bias));
        int prow = ((grow & 63) << 7) | (grow >> 6);
        (gcol < 512 ? obf0 : obf1)[(size_t)prow * 512 + (gcol & 511)] = r;
      } else {
        of[(size_t)grow * ofld + gcol] = v + bias0[gcol];
      }
    }
  }
}

// ------------------------- generic 128x128 MFMA GEMM ------------------------
// (h0 only: A bf16, B f32, raw f32 partials via z split-K)
template<int A_BF16, int B_BF16, int EPI>
__global__ __launch_bounds__(256) void k_gemm128(
    const void* __restrict__ Ap, int lda, const void* __restrict__ Bp, int ldb,
    int M, int N, int kper,
    unsigned short* __restrict__ obf0, unsigned short* __restrict__ obf1,
    float* __restrict__ of, const float* __restrict__ bias0,
    const float* __restrict__ bias1)
{
  __shared__ __align__(16) unsigned short As[128 * 32];
  __shared__ __align__(16) unsigned short Bs[128 * 32];
  const int tid = threadIdx.x;
  const int c0 = blockIdx.x * 128, r0 = blockIdx.y * 128;
  const int k0 = blockIdx.z * kper;
  if (EPI == 2) of += (size_t)blockIdx.z * M * N;

  const int lane = tid & 63, w = tid >> 6;
  const int wr = w >> 1, wc = w & 1;
  const int fr = lane & 15, fq = lane >> 4;

  f32x4 acc[4][4] = {};

  const int srow = tid >> 1, shalf = (tid & 1) * 16;

  for (int k = k0; k < k0 + kper; k += 32) {
    u16x8 a0, a1, b0, b1;
    {
      int gr = r0 + srow;
      if (gr < M) {
        if (A_BF16) {
          const unsigned short* a = (const unsigned short*)Ap + (size_t)gr * lda + k + shalf;
          a0 = *(const u16x8*)a; a1 = *(const u16x8*)(a + 8);
        } else {
          const float* a = (const float*)Ap + (size_t)gr * lda + k + shalf;
          float4 f0 = ((const float4*)a)[0], f1 = ((const float4*)a)[1];
          float4 f2 = ((const float4*)a)[2], f3 = ((const float4*)a)[3];
          a0 = pack8(f0, f1); a1 = pack8(f2, f3);
        }
      } else { a0 = zero8(); a1 = zero8(); }
    }
    {
      int gr = c0 + srow;
      if (B_BF16) {
        const unsigned short* p = (const unsigned short*)Bp + (size_t)gr * ldb + k + shalf;
        b0 = *(const u16x8*)p; b1 = *(const u16x8*)(p + 8);
      } else {
        const float* p = (const float*)Bp + (size_t)gr * ldb + k + shalf;
        float4 f0 = ((const float4*)p)[0], f1 = ((const float4*)p)[1];
        float4 f2 = ((const float4*)p)[2], f3 = ((const float4*)p)[3];
        b0 = pack8(f0, f1); b1 = pack8(f2, f3);
      }
    }
    *(u16x8*)&As[srow * 32 + shalf]     = a0;
    *(u16x8*)&As[srow * 32 + shalf + 8] = a1;
    *(u16x8*)&Bs[srow * 32 + shalf]     = b0;
    *(u16x8*)&Bs[srow * 32 + shalf + 8] = b1;
    __syncthreads();

    u16x8 af[4], bfv[4];
    #pragma unroll
    for (int mi = 0; mi < 4; mi++)
      af[mi] = *(const u16x8*)&As[(wr * 64 + mi * 16 + fr) * 32 + fq * 8];
    #pragma unroll
    for (int nj = 0; nj < 4; nj++)
      bfv[nj] = *(const u16x8*)&Bs[(wc * 64 + nj * 16 + fr) * 32 + fq * 8];
    #pragma unroll
    for (int mi = 0; mi < 4; mi++)
      #pragma unroll
      for (int nj = 0; nj < 4; nj++)
        acc[mi][nj] = __builtin_amdgcn_mfma_f32_16x16x32_bf16(
            as_bf(af[mi]), as_bf(bfv[nj]), acc[mi][nj], 0, 0, 0);
    __syncthreads();
  }

  #pragma unroll
  for (int mi = 0; mi < 4; mi++)
  #pragma unroll
  for (int nj = 0; nj < 4; nj++) {
    f32x4 a = acc[mi][nj];
    #pragma unroll
    for (int j = 0; j < 4; j++) {
      int grow = r0 + wr * 64 + mi * 16 + fq * 4 + j;
      int gcol = c0 + wc * 64 + nj * 16 + fr;
      if (grow < M) {
        float v = a[j];
        if constexpr (EPI == 1) {
          of[(size_t)grow * N + gcol] = v + bias0[gcol];
        } else if constexpr (EPI == 2) {
          of[(size_t)grow * N + gcol] = v;
        }
      }
    }
  }
}

__global__ __launch_bounds__(256) void k_reduce_h0(const float* __restrict__ part,
                                                   const float* __restrict__ b_ctx,
                                                   float* __restrict__ h,
                                                   unsigned short* __restrict__ h_bf) {
  int j = blockIdx.x * 256 + threadIdx.x;   // < 64*512
  float s = b_ctx[j & 511];
  for (int z = 0; z < 8; z++) s += part[z * 32768 + j];
  h[j] = s;
  h_bf[j] = f2bf(s);
}

// ------------------- W_f = W_ih @ W_in  fold (one-time) ---------------------
__global__ __launch_bounds__(256) void k_wf(const float* __restrict__ W_ih,
                                            const float* __restrict__ W_in,
                                            unsigned short* __restrict__ wf_att,
                                            float* __restrict__ wfx) {
  __shared__ float wl[8][512];
  int ic = blockIdx.x, jc = blockIdx.y, tid = threadIdx.x;
  for (int x = tid; x < 8 * 512; x += 256)
    wl[x >> 9][x & 511] = W_ih[(ic * 8 + (x >> 9)) * 512 + (x & 511)];
  __syncthreads();
  int j = jc * 256 + tid;
  if (j >= 1324) return;
  float acc[8] = {};
  for (int d = 0; d < 512; d++) {
    float win = W_in[d * 1324 + j];
    #pragma unroll
    for (int r = 0; r < 8; r++) acc[r] += wl[r][d] * win;
  }
  for (int r = 0; r < 8; r++) {
    int i = ic * 8 + r;
    if (j < 300) wfx[i * 300 + j] = acc[r];
    else         wf_att[i * 1024 + (j - 300)] = f2bf(acc[r]);
  }
}

__global__ __launch_bounds__(256) void k_bfull(const float* __restrict__ W_ih,
                                               const float* __restrict__ b_in,
                                               const float* __restrict__ b_ih,
                                               float* __restrict__ bfull) {
  int i = blockIdx.x * 256 + threadIdx.x;
  if (i >= 1536) return;
  float acc = b_ih[i];
  for (int d = 0; d < 512; d++) acc += W_ih[i * 512 + d] * b_in[d];
  bfull[i] = acc;
}

// gi_x[t*64+b, :] = expl[t,b,:300] @ Wfx^T
__global__ __launch_bounds__(256) void k_gix(const float* __restrict__ expl,
                                             const float* __restrict__ wfx,
                                             float* __restrict__ gi_x) {
  __shared__ float el[16][300];
  int rc = blockIdx.x, ic = blockIdx.y, tid = threadIdx.x;
  for (int x = tid; x < 16 * 300; x += 256)
    el[x / 300][x % 300] = expl[(size_t)(rc * 16 + x / 300) * 300 + (x % 300)];
  __syncthreads();
  int c = ic * 256 + tid;
  float acc[16] = {};
  for (int k = 0; k < 300; k++) {
    float wv = wfx[c * 300 + k];
    #pragma unroll
    for (int r = 0; r < 16; r++) acc[r] += el[r][k] * wv;
  }
  for (int r = 0; r < 16; r++) gi_x[(size_t)(rc * 16 + r) * 1536 + c] = acc[r];
}

// --------------------- per-step 64-row MFMA col-slice -----------------------
// C[64, ncols] = A[64, K] @ B[ncols, K]^T, one 64x64 tile per block.
// EPI 0 (K1): A=h_bf, B=wcat[2560][512]; col<1024 -> qf=tanh(v+bq), else
//             ghf = v + b_hh.   EPI 1 (K3): A=att_bf, B=wf_att; gi epilogue.
template<int EPI>
__global__ __launch_bounds__(256) void k_mv64(
    const unsigned short* __restrict__ A, int lda,
    const unsigned short* __restrict__ B, int K,
    float* __restrict__ o1, float* __restrict__ o2,
    const float* __restrict__ x1, const float* __restrict__ x2,
    const float* __restrict__ x3, int t)
{
  __shared__ __align__(16) unsigned short As[64 * 32];
  __shared__ __align__(16) unsigned short Bs[64 * 32];
  const int tid = threadIdx.x;
  const int n0 = blockIdx.x * 64;
  const int lane = tid & 63, w = tid >> 6;
  const int fr = lane & 15, fq = lane >> 4;
  f32x4 acc[4] = {};
  const int srow = tid >> 2, soff = (tid & 3) * 8;

  for (int k = 0; k < K; k += 32) {
    u16x8 av = *(const u16x8*)(A + (size_t)srow * lda + k + soff);
    u16x8 bv = *(const u16x8*)(B + (size_t)(n0 + srow) * K + k + soff);
    *(u16x8*)&As[srow * 32 + soff] = av;
    *(u16x8*)&Bs[srow * 32 + soff] = bv;
    __syncthreads();
    u16x8 af = *(const u16x8*)&As[(w * 16 + fr) * 32 + fq * 8];
    #pragma unroll
    for (int nj = 0; nj < 4; nj++) {
      u16x8 bfv = *(const u16x8*)&Bs[(nj * 16 + fr) * 32 + fq * 8];
      acc[nj] = __builtin_amdgcn_mfma_f32_16x16x32_bf16(as_bf(af), as_bf(bfv), acc[nj], 0, 0, 0);
    }
    __syncthreads();
  }
  #pragma unroll
  for (int nj = 0; nj < 4; nj++) {
    #pragma unroll
    for (int j = 0; j < 4; j++) {
      int row = w * 16 + fq * 4 + j;
      int col = n0 + nj * 16 + fr;
      float v = acc[nj][j];
      if constexpr (EPI == 0) {
        if (col < 512)       o1[(size_t)row * 1024 + col] = tanhf(v + x1[col]);
        else if (col < 1024) o1[(size_t)row * 1024 + col] = tanhf(v + x2[col - 512]);
        else                 o2[(size_t)row * 1536 + (col - 1024)] = v + x3[col - 1024];
      } else {
        o1[(size_t)row * 1536 + col] =
            v + x1[(size_t)(t * 64 + row) * 1536 + col] + x2[col];
      }
    }
  }
}

// --------------------------- attention kernel -------------------------------
// grid 128 = side*64 + b; 256 threads. qf f32 [64][1024]; keys/vals
// [b*128+tt][512] bf16 per side. Writes att_bf[b][side*512 + a].
__global__ __launch_bounds__(256) void k_att(
    const float* __restrict__ qf,
    const unsigned short* __restrict__ keys1, const unsigned short* __restrict__ keys2,
    const unsigned short* __restrict__ vals1, const unsigned short* __restrict__ vals2,
    unsigned short* __restrict__ att_bf)
{
  const int id = blockIdx.x, side = id >> 6, b = id & 63;
  const int tid = threadIdx.x;
  __shared__ float qv[512];
  __shared__ float sred[128][2];
  __shared__ float pr[128];

  for (int i = tid; i < 512; i += 256)
    qv[i] = qf[(size_t)b * 1024 + side * 512 + i];
  __syncthreads();

  const unsigned short* keys = side ? keys2 : keys1;
  {
    int tt = tid >> 1, half = tid & 1;
    const u16x8* krow = (const u16x8*)(keys + ((size_t)(b * 128 + tt)) * 512 + half * 256);
    float acc = 0.f;
    #pragma unroll 4
    for (int k8 = 0; k8 < 32; k8++) {
      u16x8 kv = krow[k8];
      #pragma unroll
      for (int jj = 0; jj < 8; jj++) acc += qv[half * 256 + k8 * 8 + jj] * bf2f(kv[jj]);
    }
    sred[tt][half] = acc;
  }
  __syncthreads();

  if (tid < 64) {
    float s0 = sred[tid][0] + sred[tid][1];
    float s1 = sred[tid + 64][0] + sred[tid + 64][1];
    float m = fmaxf(s0, s1);
    #pragma unroll
    for (int off = 32; off; off >>= 1) m = fmaxf(m, __shfl_xor(m, off));
    float e0 = __expf(s0 - m), e1 = __expf(s1 - m);
    float ss = e0 + e1;
    #pragma unroll
    for (int off = 32; off; off >>= 1) ss += __shfl_xor(ss, off);
    float inv = 1.f / ss;
    pr[tid] = e0 * inv;
    pr[tid + 64] = e1 * inv;
  }
  __syncthreads();

  const unsigned short* vals = side ? vals2 : vals1;
  {
    int a0 = tid * 2;
    float acc0 = 0.f, acc1 = 0.f;
    for (int tt = 0; tt < 128; tt++) {
      float p = pr[tt];
      unsigned v = *(const unsigned*)(vals + ((size_t)(b * 128 + tt)) * 512 + a0);
      acc0 += p * bf2f((unsigned short)(v & 0xffffu));
      acc1 += p * bf2f((unsigned short)(v >> 16));
    }
    att_bf[(size_t)b * 1024 + side * 512 + a0]     = f2bf(acc0);
    att_bf[(size_t)b * 1024 + side * 512 + a0 + 1] = f2bf(acc1);
  }
}

// ------------------------------ GRU update ----------------------------------
__global__ __launch_bounds__(512) void k_gru(
    int t, const float* __restrict__ gif, const float* __restrict__ ghf,
    float* __restrict__ hst, unsigned short* __restrict__ h_bf,
    unsigned short* __restrict__ outs_bf)
{
  const int b = blockIdx.x, d = threadIdx.x;
  float ir = gif[b*1536 + d], iz = gif[b*1536 + 512 + d], inn = gif[b*1536 + 1024 + d];
  float hr = ghf[b*1536 + d], hz = ghf[b*1536 + 512 + d], hn = ghf[b*1536 + 1024 + d];
  float ho = hst[b*512 + d];
  float r = 1.f / (1.f + expf(-(ir + hr)));
  float z = 1.f / (1.f + expf(-(iz + hz)));
  float n = tanhf(inn + r * hn);
  float hv = (1.f - z) * n + z * ho;
  hst[b*512 + d] = hv;
  unsigned short bf = f2bf(hv);
  h_bf[b*512 + d] = bf;
  outs_bf[(size_t)(t * 64 + b) * 512 + d] = bf;
}

// ---------------------------------------------------------------------------
extern "C" void kernel_launch(void* const* d_in, const int* in_sizes, int n_in,
                              void* d_out, int out_size, void* d_ws, size_t ws_size,
                              hipStream_t stream) {
  const float* expl  = (const float*)d_in[0];
  const float* enc1  = (const float*)d_in[1];
  const float* enc2  = (const float*)d_in[2];
  const float* s1e   = (const float*)d_in[3];
  const float* s2e   = (const float*)d_in[4];
  const float* W_ctx = (const float*)d_in[5];
  const float* b_ctx = (const float*)d_in[6];
  const float* Wq1   = (const float*)d_in[7];
  const float* bq1   = (const float*)d_in[8];
  const float* Wk1   = (const float*)d_in[9];
  const float* bk1   = (const float*)d_in[10];
  const float* Wv1   = (const float*)d_in[11];
  const float* bv1   = (const float*)d_in[12];
  const float* Wq2   = (const float*)d_in[13];
  const float* bq2   = (const float*)d_in[14];
  const float* Wk2   = (const float*)d_in[15];
  const float* bk2   = (const float*)d_in[16];
  const float* Wv2   = (const float*)d_in[17];
  const float* bv2   = (const float*)d_in[18];
  const float* W_in  = (const float*)d_in[19];
  const float* b_in  = (const float*)d_in[20];
  const float* W_ih  = (const float*)d_in[21];
  const float* b_ih  = (const float*)d_in[22];
  const float* W_hh  = (const float*)d_in[23];
  const float* b_hh  = (const float*)d_in[24];
  const float* W_voc = (const float*)d_in[25];
  const float* b_voc = (const float*)d_in[26];
  float* out = (float*)d_out;

  char* ws = (char*)d_ws;
  unsigned short* keys1  = (unsigned short*)(ws + 0);          // [b*128+tt][512]
  unsigned short* vals1  = (unsigned short*)(ws + 8388608);
  unsigned short* keys2  = (unsigned short*)(ws + 16777216);
  unsigned short* vals2  = (unsigned short*)(ws + 25165824);
  unsigned short* encbf  = (unsigned short*)(ws + 33554432);   // 67.1 MB
  unsigned short* wkv    = (unsigned short*)(ws + 100663296);  // 8.4 MB
  unsigned short* wvoc   = (unsigned short*)(ws + 109051904);  // 32.8 MB
  unsigned short* wcat   = (unsigned short*)(ws + 141819904);  // [2560][512] 2.62MB
  unsigned short* wf_att = (unsigned short*)(ws + 144441344);  // [1536][1024] 3.15MB
  float*          wfx    = (float*)(ws + 147587072);
  float*          bfull  = (float*)(ws + 149430272);
  float*          gi_x   = (float*)(ws + 149436416);           // 12.6 MB
  unsigned short* ctx_bf = (unsigned short*)(ws + 162019328);
  float*          part   = (float*)(ws + 164116480);
  float*          hst    = (float*)(ws + 165165056);           // 128 KB
  unsigned short* h_bf   = (unsigned short*)(ws + 165296128);  // 64 KB
  float*          qf     = (float*)(ws + 165361664);           // 256 KB
  float*          ghf    = (float*)(ws + 165623808);           // 384 KB
  float*          gif    = (float*)(ws + 166017024);           // 384 KB
  unsigned short* att_bf = (unsigned short*)(ws + 166410240);  // 128 KB
  unsigned short* outs_bf= (unsigned short*)(ws + 166541312);  // 2 MB
  // end ~168.6 MB

  auto cvt = [&](const float* s, unsigned short* d, int n) {
    k_cvt<<<(n + 1023) / 1024, 256, 0, stream>>>(s, d, n);
  };

  // ---- keys/vals side 1 ----
  cvt(enc1, encbf, 8192 * 4096);
  cvt(Wk1, wkv, 512 * 4096);
  cvt(Wv1, wkv + 512 * 4096, 512 * 4096);
  k_gemm_lds<0><<<dim3(64, 8), 256, 0, stream>>>(
      encbf, 4096, wkv, 4096, 4096, keys1, vals1, nullptr, 0, bk1, bv1);
  // ---- keys/vals side 2 ----
  cvt(enc2, encbf, 8192 * 4096);
  cvt(Wk2, wkv, 512 * 4096);
  cvt(Wv2, wkv + 512 * 4096, 512 * 4096);
  k_gemm_lds<0><<<dim3(64, 8), 256, 0, stream>>>(
      encbf, 4096, wkv, 4096, 4096, keys2, vals2, nullptr, 0, bk2, bv2);

  // ---- weight converts ----
  cvt(W_voc, wvoc, 32000 * 512);
  cvt(Wq1, wcat, 512 * 512);                     // wcat rows 0..511
  cvt(Wq2, wcat + 512 * 512, 512 * 512);         // rows 512..1023
  cvt(W_hh, wcat + 1024 * 512, 1536 * 512);      // rows 1024..2559

  // ---- Wf fold + gi_x ----
  k_wf<<<dim3(192, 6), 256, 0, stream>>>(W_ih, W_in, wf_att, wfx);
  k_bfull<<<6, 256, 0, stream>>>(W_ih, b_in, b_ih, bfull);
  k_gix<<<dim3(128, 6), 256, 0, stream>>>(expl, wfx, gi_x);

  // ---- h0 ----
  k_build_ctx<<<4096, 256, 0, stream>>>(s1e, s2e, ctx_bf);
  k_gemm128<1, 0, 2><<<dim3(4, 1, 8), 256, 0, stream>>>(
      ctx_bf, 16384, W_ctx, 16384, 64, 512, 2048,
      nullptr, nullptr, part, nullptr, nullptr);
  k_reduce_h0<<<128, 256, 0, stream>>>(part, b_ctx, hst, h_bf);

  // ---- recurrence: 4 col-sliced kernels per step ----
  for (int t = 0; t < 32; t++) {
    k_mv64<0><<<40, 256, 0, stream>>>(h_bf, 512, wcat, 512,
                                      qf, ghf, bq1, bq2, b_hh, 0);
    k_att<<<128, 256, 0, stream>>>(qf, keys1, keys2, vals1, vals2, att_bf);
    k_mv64<1><<<24, 256, 0, stream>>>(att_bf, 1024, wf_att, 1024,
                                      gif, nullptr, gi_x, bfull, nullptr, t);
    k_gru<<<64, 512, 0, stream>>>(t, gif, ghf, hst, h_bf, outs_bf);
  }

  // ---- logits = outs @ W_voc^T + b_voc ----
  k_gemm_lds<1><<<dim3(16, 250), 256, 0, stream>>>(
      outs_bf, 512, wvoc, 512, 512, nullptr, nullptr, out, 32000, b_voc, nullptr);
}